// Round 1
// baseline (736.045 us; speedup 1.0000x reference)
//
#include <hip/hip_runtime.h>
#include <stdint.h>

typedef unsigned short u16;
typedef __attribute__((ext_vector_type(8))) short short8;   // 8 x bf16 MFMA operand (guide §3)
typedef __attribute__((ext_vector_type(4))) float f32x4;    // MFMA accumulator
typedef __attribute__((ext_vector_type(4))) uint32_t u32x4;

#define KEXP   8
#define LATENT 256
#define CONDD  1024
#define HID    128
#define EIN    1281
#define EINP   1344   // 21 * 64, zero padded
#define NCH    21
#define BM     64

// round-to-nearest-even fp32 -> bf16
__device__ __forceinline__ u16 f2bf(float x) {
  uint32_t v = __float_as_uint(x);
  v += 0x7fffu + ((v >> 16) & 1u);
  return (u16)(v >> 16);
}

// async global->LDS, 16B per lane; LDS dest = wave-uniform base + lane*16
__device__ __forceinline__ void async16(const void* g, void* l) {
  __builtin_amdgcn_global_load_lds(
      (const __attribute__((address_space(1))) void*)g,
      (__attribute__((address_space(3))) void*)l, 16, 0, 0);
}

__device__ __forceinline__ float silu(float x) {
  return x / (1.f + __expf(-x));
}

// ---------------------------------------------------------------------------
// Weight conversion/transpose pre-pass (runs every call; tiny: ~1.8M elements)
// W1t[k][h][d<EINP]  = W1[k][d][h] (0 for d>=EIN)
// W2t[k][g][h]       = W2[k][h][g]
// W3t[k][l][g]       = W3[k][g][l]
// ---------------------------------------------------------------------------
__global__ void conv_w(const float* __restrict__ W1, const float* __restrict__ W2,
                       const float* __restrict__ W3,
                       u16* __restrict__ W1t, u16* __restrict__ W2t, u16* __restrict__ W3t) {
  const int N1 = KEXP * HID * EINP;   // 1376256
  const int N2 = KEXP * HID * HID;    // 131072
  const int N3 = KEXP * LATENT * HID; // 262144
  int i = blockIdx.x * 256 + threadIdx.x;
  if (i < N1) {
    int k = i / (HID * EINP);
    int r = i % (HID * EINP);
    int h = r / EINP;
    int d = r % EINP;
    float v = (d < EIN) ? W1[((size_t)k * EIN + d) * HID + h] : 0.f;
    W1t[i] = f2bf(v);
  } else if (i < N1 + N2) {
    int j = i - N1;
    int k = j / (HID * HID);
    int r = j % (HID * HID);
    int g = r / HID;
    int h = r % HID;
    W2t[j] = f2bf(W2[((size_t)k * HID + h) * HID + g]);
  } else if (i < N1 + N2 + N3) {
    int j = i - N1 - N2;
    int k = j / (LATENT * HID);
    int r = j % (LATENT * HID);
    int l = r / HID;
    int g = r % HID;
    W3t[j] = f2bf(W3[((size_t)k * HID + g) * LATENT + l]);
  }
}

// ---------------------------------------------------------------------------
// Fused MoE kernel. Block = 64 rows x 256 threads (4 waves), loops 8 experts.
// MFMA 16x16x32 bf16. Wave w owns output cols [w*32, w*32+32) of each 128-wide
// phase; phase-3 (256 wide) is done in two 128-col halves.
// Fragment layouts (guide §3, m89/m91/m120 verified):
//   A: lane holds A[m=lane&15][k=(lane>>4)*8 + j]
//   B: lane holds B[k=(lane>>4)*8 + j][n=lane&15]
//   C/D: lane holds C[row=(lane>>4)*4 + r][col=lane&15]
// LDS swizzle: within each row, 16B group at position p holds source group
// p ^ (row & (groups_per_row-1 capped)) so frag ds_read_b128 is 2-way max.
// ---------------------------------------------------------------------------
__global__ __launch_bounds__(256, 2)
void moe_fused(const float* __restrict__ cond, const float* __restrict__ u,
               const float* __restrict__ tau, const float* __restrict__ p_hat,
               const u16* __restrict__ W1t, const float* __restrict__ b1,
               const u16* __restrict__ W2t, const float* __restrict__ b2,
               const u16* __restrict__ W3t, const float* __restrict__ b3,
               float* __restrict__ out) {
  __shared__ struct {
    float Ps[BM * KEXP];                          // 2 KB gate tile
    u16 HsA[BM * 136];                            // 17 KB  H1 (stride 136, +8 pad)
    union { u16 Xs[BM * 64]; u16 HsB[BM * 136]; };// 17 KB  X chunk / H2
    u16 Wbuf[128 * 128];                          // 32 KB  W1 chunk / W2 / W3 half
  } sm;                                           // 68 KB total -> 2 blocks/CU

  const int tid  = threadIdx.x;
  const int wave = tid >> 6;
  const int lane = tid & 63;
  const int q    = lane >> 4;   // quad
  const int ln   = lane & 15;
  const int row0 = blockIdx.x * BM;

  // stage gate tile (B,8) fp32
  sm.Ps[tid]       = p_hat[(size_t)row0 * KEXP + tid];
  sm.Ps[tid + 256] = p_hat[(size_t)row0 * KEXP + 256 + tid];

  const f32x4 fz = {0.f, 0.f, 0.f, 0.f};
  f32x4 accO[4][4];   // [m-tile][half*2+n] -> 64 fp32/lane, persists across experts
  #pragma unroll
  for (int m = 0; m < 4; ++m)
    #pragma unroll
    for (int j = 0; j < 4; ++j) accO[m][j] = fz;

  __syncthreads();

  #pragma unroll 1
  for (int k = 0; k < KEXP; ++k) {
    // gate values for this lane's 16 C-rows (LDS broadcast reads)
    float pv[4][4];
    #pragma unroll
    for (int m = 0; m < 4; ++m)
      #pragma unroll
      for (int r = 0; r < 4; ++r)
        pv[m][r] = sm.Ps[(m * 16 + q * 4 + r) * KEXP + k];

    // ================= phase 1: H1 = silu(X @ W1_k + b1) =================
    f32x4 acc1[4][2];
    #pragma unroll
    for (int m = 0; m < 4; ++m) { acc1[m][0] = fz; acc1[m][1] = fz; }

    const u16* w1k = W1t + (size_t)k * HID * EINP;

    #pragma unroll 1
    for (int ic = 0; ic < NCH; ++ic) {
      const int d0 = ic * 64;
      // ---- stage Xs: 64 rows x 64 cols bf16, 8-group XOR swizzle ----
      #pragma unroll
      for (int i = 0; i < 2; ++i) {
        int lin  = tid + i * 256;       // 0..511 (512 groups of 8)
        int r    = lin >> 3;            // row
        int gsw  = lin & 7;             // stored group position
        int gsrc = gsw ^ (r & 7);       // source group
        float f0, f1, f2, f3, f4, f5, f6, f7;
        if (d0 < 256) {                 // u region (cols 0..255)
          const float4* p = (const float4*)(u + (size_t)(row0 + r) * LATENT + d0 + gsrc * 8);
          float4 A = p[0], Bv = p[1];
          f0 = A.x; f1 = A.y; f2 = A.z; f3 = A.w;
          f4 = Bv.x; f5 = Bv.y; f6 = Bv.z; f7 = Bv.w;
        } else if (d0 < 1280) {         // cond region (cols 256..1279)
          const float4* p = (const float4*)(cond + (size_t)(row0 + r) * CONDD + (d0 - 256) + gsrc * 8);
          float4 A = p[0], Bv = p[1];
          f0 = A.x; f1 = A.y; f2 = A.z; f3 = A.w;
          f4 = Bv.x; f5 = Bv.y; f6 = Bv.z; f7 = Bv.w;
        } else {                        // col 1280 = tau, 1281.. = 0
          float tv = tau[row0 + r];
          f0 = (gsrc == 0) ? tv : 0.f;
          f1 = f2 = f3 = f4 = f5 = f6 = f7 = 0.f;
        }
        u32x4 pk;
        pk[0] = (uint32_t)f2bf(f0) | ((uint32_t)f2bf(f1) << 16);
        pk[1] = (uint32_t)f2bf(f2) | ((uint32_t)f2bf(f3) << 16);
        pk[2] = (uint32_t)f2bf(f4) | ((uint32_t)f2bf(f5) << 16);
        pk[3] = (uint32_t)f2bf(f6) | ((uint32_t)f2bf(f7) << 16);
        *(u32x4*)(&sm.Xs[r * 64 + gsw * 8]) = pk;
      }
      // ---- stage W1 chunk: 128 h-rows x 64 d, swizzled, async 16B ----
      {
        int rloc = lane >> 3;           // row within 8-row slab (== h&7)
        int gsw  = lane & 7;
        int gsrc = gsw ^ rloc;
        #pragma unroll
        for (int i = 0; i < 4; ++i) {
          int hbase = (wave * 4 + i) * 8;
          async16(w1k + (size_t)(hbase + rloc) * EINP + d0 + gsrc * 8,
                  &sm.Wbuf[hbase * 64]);
        }
      }
      __syncthreads();
      // ---- 2 k-steps of MFMA ----
      #pragma unroll
      for (int ks = 0; ks < 2; ++ks) {
        short8 a[4], b[2];
        #pragma unroll
        for (int m = 0; m < 4; ++m) {
          int rr = m * 16 + ln;
          int g  = (ks * 4 + q) ^ (rr & 7);
          a[m] = *(const short8*)(&sm.Xs[rr * 64 + g * 8]);
        }
        #pragma unroll
        for (int n = 0; n < 2; ++n) {
          int hh = wave * 32 + n * 16 + ln;
          int g  = (ks * 4 + q) ^ (hh & 7);
          b[n] = *(const short8*)(&sm.Wbuf[hh * 64 + g * 8]);
        }
        #pragma unroll
        for (int m = 0; m < 4; ++m)
          #pragma unroll
          for (int n = 0; n < 2; ++n)
            acc1[m][n] = __builtin_amdgcn_mfma_f32_16x16x32_bf16(a[m], b[n], acc1[m][n], 0, 0, 0);
      }
      __syncthreads();
    }

    // bias + silu -> HsA (H1, bf16, stride 136)
    #pragma unroll
    for (int n = 0; n < 2; ++n) {
      int col = wave * 32 + n * 16 + ln;
      float bv = b1[k * HID + col];
      #pragma unroll
      for (int m = 0; m < 4; ++m)
        #pragma unroll
        for (int r = 0; r < 4; ++r)
          sm.HsA[(m * 16 + q * 4 + r) * 136 + col] = f2bf(silu(acc1[m][n][r] + bv));
    }
    // stage W2_k: 128 g-rows x 128 h, 16-group swizzle, async 16B
    {
      int rloc = lane >> 4;
      int pos  = lane & 15;
      const u16* w2k = W2t + (size_t)k * HID * HID;
      #pragma unroll
      for (int i = 0; i < 8; ++i) {
        int rbase = (wave * 8 + i) * 4;
        int row = rbase + rloc;
        int src = pos ^ (row & 15);
        async16(w2k + (size_t)row * HID + src * 8, &sm.Wbuf[rbase * HID]);
      }
    }
    __syncthreads();

    // ================= phase 2: H2 = silu(H1 @ W2_k + b2) =================
    f32x4 acc2[4][2];
    #pragma unroll
    for (int m = 0; m < 4; ++m) { acc2[m][0] = fz; acc2[m][1] = fz; }
    #pragma unroll
    for (int ks = 0; ks < 4; ++ks) {
      short8 a[4], b[2];
      #pragma unroll
      for (int m = 0; m < 4; ++m)
        a[m] = *(const short8*)(&sm.HsA[(m * 16 + ln) * 136 + ks * 32 + q * 8]);
      #pragma unroll
      for (int n = 0; n < 2; ++n) {
        int gg = wave * 32 + n * 16 + ln;
        int src = (ks * 4 + q) ^ (gg & 15);
        b[n] = *(const short8*)(&sm.Wbuf[gg * 128 + src * 8]);
      }
      #pragma unroll
      for (int m = 0; m < 4; ++m)
        #pragma unroll
        for (int n = 0; n < 2; ++n)
          acc2[m][n] = __builtin_amdgcn_mfma_f32_16x16x32_bf16(a[m], b[n], acc2[m][n], 0, 0, 0);
    }
    __syncthreads();   // Wbuf reads done; safe to restage

    // bias + silu -> HsB (H2)
    #pragma unroll
    for (int n = 0; n < 2; ++n) {
      int col = wave * 32 + n * 16 + ln;
      float bv = b2[k * HID + col];
      #pragma unroll
      for (int m = 0; m < 4; ++m)
        #pragma unroll
        for (int r = 0; r < 4; ++r)
          sm.HsB[(m * 16 + q * 4 + r) * 136 + col] = f2bf(silu(acc2[m][n][r] + bv));
    }
    // stage W3_k half 0 (l-rows 0..127)
    const u16* w3k = W3t + (size_t)k * LATENT * HID;
    {
      int rloc = lane >> 4;
      int pos  = lane & 15;
      #pragma unroll
      for (int i = 0; i < 8; ++i) {
        int rbase = (wave * 8 + i) * 4;
        int row = rbase + rloc;
        int src = pos ^ (row & 15);
        async16(w3k + (size_t)row * HID + src * 8, &sm.Wbuf[rbase * HID]);
      }
    }
    __syncthreads();

    // ================= phase 3: O += p * (H2 @ W3_k + b3) =================
    #pragma unroll
    for (int hf = 0; hf < 2; ++hf) {
      f32x4 acc3[4][2];
      #pragma unroll
      for (int m = 0; m < 4; ++m) { acc3[m][0] = fz; acc3[m][1] = fz; }
      #pragma unroll
      for (int ks = 0; ks < 4; ++ks) {
        short8 a[4], b[2];
        #pragma unroll
        for (int m = 0; m < 4; ++m)
          a[m] = *(const short8*)(&sm.HsB[(m * 16 + ln) * 136 + ks * 32 + q * 8]);
        #pragma unroll
        for (int n = 0; n < 2; ++n) {
          int ll = wave * 32 + n * 16 + ln;   // l within half
          int src = (ks * 4 + q) ^ (ll & 15);
          b[n] = *(const short8*)(&sm.Wbuf[ll * 128 + src * 8]);
        }
        #pragma unroll
        for (int m = 0; m < 4; ++m)
          #pragma unroll
          for (int n = 0; n < 2; ++n)
            acc3[m][n] = __builtin_amdgcn_mfma_f32_16x16x32_bf16(a[m], b[n], acc3[m][n], 0, 0, 0);
      }
      // gate-weighted accumulate (+ b3 folded per expert)
      #pragma unroll
      for (int n = 0; n < 2; ++n) {
        int col = hf * 128 + wave * 32 + n * 16 + ln;
        float b3v = b3[k * LATENT + col];
        #pragma unroll
        for (int m = 0; m < 4; ++m)
          #pragma unroll
          for (int r = 0; r < 4; ++r)
            accO[m][hf * 2 + n][r] += pv[m][r] * (acc3[m][n][r] + b3v);
      }
      if (hf == 0) {
        __syncthreads();   // half-0 Wbuf reads done
        int rloc = lane >> 4;
        int pos  = lane & 15;
        #pragma unroll
        for (int i = 0; i < 8; ++i) {
          int rbase = (wave * 8 + i) * 4;
          int row = rbase + rloc;
          int src = pos ^ (row & 15);
          async16(w3k + (size_t)(128 + row) * HID + src * 8, &sm.Wbuf[rbase * HID]);
        }
        __syncthreads();
      }
    }
    __syncthreads();   // protect Xs/HsB alias + Wbuf before next expert
  }

  // ---- write O (fp32, B x 256) ----
  #pragma unroll
  for (int m = 0; m < 4; ++m)
    #pragma unroll
    for (int j = 0; j < 4; ++j) {
      int col = (j >> 1) * 128 + wave * 32 + (j & 1) * 16 + ln;
      #pragma unroll
      for (int r = 0; r < 4; ++r) {
        int row = row0 + m * 16 + q * 4 + r;
        out[(size_t)row * LATENT + col] = accO[m][j][r];
      }
    }
}

extern "C" void kernel_launch(void* const* d_in, const int* in_sizes, int n_in,
                              void* d_out, int out_size, void* d_ws, size_t ws_size,
                              hipStream_t stream) {
  const float* cond  = (const float*)d_in[0];
  const float* u     = (const float*)d_in[1];
  const float* tau   = (const float*)d_in[2];
  const float* p_hat = (const float*)d_in[3];
  const float* W1    = (const float*)d_in[4];
  const float* b1    = (const float*)d_in[5];
  const float* W2    = (const float*)d_in[6];
  const float* b2    = (const float*)d_in[7];
  const float* W3    = (const float*)d_in[8];
  const float* b3    = (const float*)d_in[9];
  float* out = (float*)d_out;

  const int N1 = KEXP * HID * EINP;
  const int N2 = KEXP * HID * HID;
  const int N3 = KEXP * LATENT * HID;
  if (ws_size < (size_t)(N1 + N2 + N3) * sizeof(u16)) return;  // need ~3.4 MB scratch

  u16* W1t = (u16*)d_ws;
  u16* W2t = W1t + N1;
  u16* W3t = W2t + N2;

  const int convN = N1 + N2 + N3;                 // 1769472
  conv_w<<<(convN + 255) / 256, 256, 0, stream>>>(W1, W2, W3, W1t, W2t, W3t);
  moe_fused<<<32768 / BM, 256, 0, stream>>>(cond, u, tau, p_hat,
                                            W1t, b1, W2t, b2, W3t, b3, out);
}

// Round 2
// 572.675 us; speedup vs baseline: 1.2853x; 1.2853x over previous
//
#include <hip/hip_runtime.h>
#include <stdint.h>

typedef unsigned short u16;
typedef __attribute__((ext_vector_type(8))) short short8;   // 8 x bf16 MFMA operand
typedef __attribute__((ext_vector_type(4))) float f32x4;    // MFMA accumulator
typedef __attribute__((ext_vector_type(4))) uint32_t u32x4;

#define KEXP   8
#define LATENT 256
#define CONDD  1024
#define HID    128
#define EIN    1281
#define EINP   1344   // 21*64, zero padded
#define NCH    21
#define BM     64     // moe_tail row tile
#define NTOT   1024   // KEXP*HID

__device__ __forceinline__ u16 f2bf(float x) {              // RNE fp32->bf16
  uint32_t v = __float_as_uint(x);
  v += 0x7fffu + ((v >> 16) & 1u);
  return (u16)(v >> 16);
}

__device__ __forceinline__ void async16(const void* g, void* l) {
  __builtin_amdgcn_global_load_lds(
      (const __attribute__((address_space(1))) void*)g,
      (__attribute__((address_space(3))) void*)l, 16, 0, 0);
}

__device__ __forceinline__ float silu(float x) { return x / (1.f + __expf(-x)); }

// ---------------------------------------------------------------------------
// Coalesced 32x32 LDS-tiled transpose of W1/W2/W3 -> bf16, [k][d][h]->[k][h][d]
// W1: D=1281(pad 1344), H=128 | W2: D=128, H=128 | W3: D=128, H=256
// ---------------------------------------------------------------------------
#define W1_TILES (KEXP * 42 * 4)    // 1344
#define W2_TILES (KEXP * 4 * 4)     // 128
#define W3_TILES (KEXP * 4 * 8)     // 256

__global__ void conv_w(const float* __restrict__ W1, const float* __restrict__ W2,
                       const float* __restrict__ W3,
                       u16* __restrict__ W1t, u16* __restrict__ W2t, u16* __restrict__ W3t) {
  __shared__ float t[32][33];
  int bid = blockIdx.x;
  const float* src; u16* dst;
  int D, Dp, H, k, dt, ht;
  if (bid < W1_TILES) {
    k = bid / (42 * 4); int r = bid % (42 * 4);
    dt = r / 4; ht = r % 4;
    D = EIN; Dp = EINP; H = HID;
    src = W1 + (size_t)k * EIN * HID;
    dst = W1t + (size_t)k * HID * EINP;
  } else if (bid < W1_TILES + W2_TILES) {
    int j = bid - W1_TILES;
    k = j / 16; int r = j % 16;
    dt = r / 4; ht = r % 4;
    D = HID; Dp = HID; H = HID;
    src = W2 + (size_t)k * HID * HID;
    dst = W2t + (size_t)k * HID * HID;
  } else {
    int j = bid - W1_TILES - W2_TILES;
    k = j / 32; int r = j % 32;
    dt = r / 8; ht = r % 8;
    D = HID; Dp = HID; H = LATENT;
    src = W3 + (size_t)k * HID * LATENT;
    dst = W3t + (size_t)k * LATENT * HID;
  }
  int tx = threadIdx.x & 31, ty = threadIdx.x >> 5;   // 32 x 8
  int d0 = dt * 32, h0 = ht * 32;
  #pragma unroll
  for (int s = 0; s < 4; ++s) {
    int d = d0 + ty + s * 8;
    t[ty + s * 8][tx] = (d < D) ? src[(size_t)d * H + h0 + tx] : 0.f;
  }
  __syncthreads();
  #pragma unroll
  for (int s = 0; s < 4; ++s) {
    int h = h0 + ty + s * 8;
    dst[(size_t)h * Dp + d0 + tx] = f2bf(t[tx][ty + s * 8]);
  }
}

// ---------------------------------------------------------------------------
// Kernel A: H1[b][k*128+h] = silu(X @ W1t + b1), bf16 out.
// M=32768, N=1024 (8 experts x 128), K=1344. 128x128 tile, BK=64, 4 waves,
// wave quadrant 64x64 (acc 4x4). X converted fp32->bf16 during staging;
// W1t staged via global_load_lds width=16. XOR-swizzled 16B groups.
// ---------------------------------------------------------------------------
__global__ __launch_bounds__(256, 3)
void h1_gemm(const float* __restrict__ cond, const float* __restrict__ uu,
             const float* __restrict__ tau, const u16* __restrict__ W1t,
             const float* __restrict__ b1, u16* __restrict__ H1) {
  __shared__ union {
    struct { u16 As[128 * 64]; u16 Bs[128 * 64]; } s;   // 32 KB staging
    u16 Cs[128 * 136];                                  // 34.8 KB epilogue
  } sm;

  const int tid  = threadIdx.x;
  const int wave = tid >> 6;
  const int lane = tid & 63;
  const int q    = lane >> 4;
  const int ln   = lane & 15;
  const int wm   = wave >> 1, wn = wave & 1;
  const int bx   = blockIdx.x >> 3;      // 8 consecutive blocks share the X m-tile
  const int by   = blockIdx.x & 7;       // expert
  const int m0   = bx * 128, n0 = by * 128;
  const u16* w1k = W1t + (size_t)by * HID * EINP;

  const f32x4 fz = {0.f, 0.f, 0.f, 0.f};
  f32x4 acc[4][4];
  #pragma unroll
  for (int m = 0; m < 4; ++m)
    #pragma unroll
    for (int n = 0; n < 4; ++n) acc[m][n] = fz;

  #pragma unroll 1
  for (int ic = 0; ic < NCH; ++ic) {
    const int d0 = ic * 64;
    // ---- stage A (X -> bf16): 128 rows x 64 cols, 8-group XOR swizzle ----
    #pragma unroll
    for (int i = 0; i < 4; ++i) {
      int lin  = tid + i * 256;        // 0..1023
      int row  = lin >> 3;
      int gsw  = lin & 7;
      int gsrc = gsw ^ (row & 7);
      int gr   = m0 + row;
      float f0, f1, f2, f3, f4, f5, f6, f7;
      if (d0 < 256) {
        const float4* p = (const float4*)(uu + (size_t)gr * LATENT + d0 + gsrc * 8);
        float4 A = p[0], Bv = p[1];
        f0 = A.x; f1 = A.y; f2 = A.z; f3 = A.w; f4 = Bv.x; f5 = Bv.y; f6 = Bv.z; f7 = Bv.w;
      } else if (d0 < 1280) {
        const float4* p = (const float4*)(cond + (size_t)gr * CONDD + (d0 - 256) + gsrc * 8);
        float4 A = p[0], Bv = p[1];
        f0 = A.x; f1 = A.y; f2 = A.z; f3 = A.w; f4 = Bv.x; f5 = Bv.y; f6 = Bv.z; f7 = Bv.w;
      } else {
        float tv = tau[gr];
        f0 = (gsrc == 0) ? tv : 0.f;
        f1 = f2 = f3 = f4 = f5 = f6 = f7 = 0.f;
      }
      u32x4 pk;
      pk[0] = (uint32_t)f2bf(f0) | ((uint32_t)f2bf(f1) << 16);
      pk[1] = (uint32_t)f2bf(f2) | ((uint32_t)f2bf(f3) << 16);
      pk[2] = (uint32_t)f2bf(f4) | ((uint32_t)f2bf(f5) << 16);
      pk[3] = (uint32_t)f2bf(f6) | ((uint32_t)f2bf(f7) << 16);
      *(u32x4*)(&sm.s.As[row * 64 + gsw * 8]) = pk;
    }
    // ---- stage B (W1t): 128 n-rows x 64 d via async16, swizzled ----
    {
      int rloc = lane >> 3;
      int gsw  = lane & 7;
      int gsrc = gsw ^ rloc;            // row&7 == rloc (8-row slabs)
      #pragma unroll
      for (int i = 0; i < 4; ++i) {
        int rbase = (wave * 4 + i) * 8;
        async16(w1k + (size_t)(n0 * 0 + rbase + rloc) * EINP + d0 + gsrc * 8,
                &sm.s.Bs[rbase * 64]);
      }
    }
    __syncthreads();
    #pragma unroll
    for (int ks = 0; ks < 2; ++ks) {
      short8 a[4], b[4];
      #pragma unroll
      for (int m = 0; m < 4; ++m) {
        int r = wm * 64 + m * 16 + ln;
        int g = (ks * 4 + q) ^ (r & 7);
        a[m] = *(const short8*)(&sm.s.As[r * 64 + g * 8]);
      }
      #pragma unroll
      for (int n = 0; n < 4; ++n) {
        int c = wn * 64 + n * 16 + ln;
        int g = (ks * 4 + q) ^ (c & 7);
        b[n] = *(const short8*)(&sm.s.Bs[c * 64 + g * 8]);
      }
      #pragma unroll
      for (int m = 0; m < 4; ++m)
        #pragma unroll
        for (int n = 0; n < 4; ++n)
          acc[m][n] = __builtin_amdgcn_mfma_f32_16x16x32_bf16(a[m], b[n], acc[m][n], 0, 0, 0);
    }
    __syncthreads();
  }

  // ---- epilogue: silu + bias -> bf16, LDS transpose for 16B stores ----
  #pragma unroll
  for (int n = 0; n < 4; ++n) {
    int col = wn * 64 + n * 16 + ln;
    float bv = b1[n0 + col];
    #pragma unroll
    for (int m = 0; m < 4; ++m)
      #pragma unroll
      for (int r = 0; r < 4; ++r)
        sm.Cs[(wm * 64 + m * 16 + q * 4 + r) * 136 + col] = f2bf(silu(acc[m][n][r] + bv));
  }
  __syncthreads();
  #pragma unroll
  for (int i = 0; i < 8; ++i) {
    int lin = tid + i * 256;           // 0..2047
    int row = lin >> 4;
    int grp = lin & 15;
    u32x4 v = *(const u32x4*)(&sm.Cs[row * 136 + grp * 8]);
    *(u32x4*)(H1 + (size_t)(m0 + row) * NTOT + n0 + grp * 8) = v;
  }
}

// ---------------------------------------------------------------------------
// Kernel B: per 64-row tile, loop experts: H2 = silu(H1@W2+b2),
// O += p * (H2@W3 + b3). H1/W2/W3 staged via async16 (bf16).
// ---------------------------------------------------------------------------
__global__ __launch_bounds__(256, 2)
void moe_tail(const u16* __restrict__ H1, const float* __restrict__ p_hat,
              const u16* __restrict__ W2t, const float* __restrict__ b2,
              const u16* __restrict__ W3t, const float* __restrict__ b3,
              float* __restrict__ out) {
  __shared__ struct {
    float Ps[BM * KEXP];     // 2 KB
    u16 H1s[BM * 128];       // 16 KB, 16-group XOR swizzle
    u16 H2s[BM * 136];       // 17.4 KB, +8 pad
    u16 Wbuf[128 * 128];     // 32 KB
  } sm;

  const int tid  = threadIdx.x;
  const int wave = tid >> 6;
  const int lane = tid & 63;
  const int q    = lane >> 4;
  const int ln   = lane & 15;
  const int row0 = blockIdx.x * BM;

  sm.Ps[tid]       = p_hat[(size_t)row0 * KEXP + tid];
  sm.Ps[tid + 256] = p_hat[(size_t)row0 * KEXP + 256 + tid];

  const f32x4 fz = {0.f, 0.f, 0.f, 0.f};
  f32x4 accO[4][4];
  #pragma unroll
  for (int m = 0; m < 4; ++m)
    #pragma unroll
    for (int j = 0; j < 4; ++j) accO[m][j] = fz;

  __syncthreads();

  const int rloc = lane >> 4;      // staging helpers (4-row slabs, 16 groups)
  const int pos  = lane & 15;

  #pragma unroll 1
  for (int k = 0; k < KEXP; ++k) {
    float pv[4][4];
    #pragma unroll
    for (int m = 0; m < 4; ++m)
      #pragma unroll
      for (int r = 0; r < 4; ++r)
        pv[m][r] = sm.Ps[(m * 16 + q * 4 + r) * KEXP + k];

    // ---- stage H1 tile (64x128) + W2_k (128x128) ----
    #pragma unroll
    for (int i = 0; i < 4; ++i) {
      int rbase = (wave * 4 + i) * 4;
      int row = rbase + rloc;
      int src = pos ^ (row & 15);
      async16(H1 + (size_t)(row0 + row) * NTOT + k * HID + src * 8, &sm.H1s[rbase * 128]);
    }
    const u16* w2k = W2t + (size_t)k * HID * HID;
    #pragma unroll
    for (int i = 0; i < 8; ++i) {
      int rbase = (wave * 8 + i) * 4;
      int row = rbase + rloc;
      int src = pos ^ (row & 15);
      async16(w2k + (size_t)row * HID + src * 8, &sm.Wbuf[rbase * HID]);
    }
    __syncthreads();

    // ---- phase 2: H2 = silu(H1 @ W2 + b2) ----
    f32x4 acc2[4][2];
    #pragma unroll
    for (int m = 0; m < 4; ++m) { acc2[m][0] = fz; acc2[m][1] = fz; }
    #pragma unroll
    for (int ks = 0; ks < 4; ++ks) {
      short8 a[4], b[2];
      #pragma unroll
      for (int m = 0; m < 4; ++m) {
        int g = (ks * 4 + q) ^ ln;     // row&15 == ln
        a[m] = *(const short8*)(&sm.H1s[(m * 16 + ln) * 128 + g * 8]);
      }
      #pragma unroll
      for (int n = 0; n < 2; ++n) {
        int gg = wave * 32 + n * 16 + ln;
        int src = (ks * 4 + q) ^ (gg & 15);
        b[n] = *(const short8*)(&sm.Wbuf[gg * 128 + src * 8]);
      }
      #pragma unroll
      for (int m = 0; m < 4; ++m)
        #pragma unroll
        for (int n = 0; n < 2; ++n)
          acc2[m][n] = __builtin_amdgcn_mfma_f32_16x16x32_bf16(a[m], b[n], acc2[m][n], 0, 0, 0);
    }
    __syncthreads();   // Wbuf/H1s reads done

    // ---- H2 -> LDS + stage W3 half 0 ----
    #pragma unroll
    for (int n = 0; n < 2; ++n) {
      int col = wave * 32 + n * 16 + ln;
      float bv = b2[k * HID + col];
      #pragma unroll
      for (int m = 0; m < 4; ++m)
        #pragma unroll
        for (int r = 0; r < 4; ++r)
          sm.H2s[(m * 16 + q * 4 + r) * 136 + col] = f2bf(silu(acc2[m][n][r] + bv));
    }
    const u16* w3k = W3t + (size_t)k * LATENT * HID;
    #pragma unroll
    for (int i = 0; i < 8; ++i) {
      int rbase = (wave * 8 + i) * 4;
      int row = rbase + rloc;
      int src = pos ^ (row & 15);
      async16(w3k + (size_t)row * HID + src * 8, &sm.Wbuf[rbase * HID]);
    }
    __syncthreads();

    // ---- phase 3: O += p * (H2 @ W3 + b3), two 128-col halves ----
    #pragma unroll
    for (int hf = 0; hf < 2; ++hf) {
      f32x4 acc3[4][2];
      #pragma unroll
      for (int m = 0; m < 4; ++m) { acc3[m][0] = fz; acc3[m][1] = fz; }
      #pragma unroll
      for (int ks = 0; ks < 4; ++ks) {
        short8 a[4], b[2];
        #pragma unroll
        for (int m = 0; m < 4; ++m)
          a[m] = *(const short8*)(&sm.H2s[(m * 16 + ln) * 136 + ks * 32 + q * 8]);
        #pragma unroll
        for (int n = 0; n < 2; ++n) {
          int ll = wave * 32 + n * 16 + ln;
          int src = (ks * 4 + q) ^ (ll & 15);
          b[n] = *(const short8*)(&sm.Wbuf[ll * 128 + src * 8]);
        }
        #pragma unroll
        for (int m = 0; m < 4; ++m)
          #pragma unroll
          for (int n = 0; n < 2; ++n)
            acc3[m][n] = __builtin_amdgcn_mfma_f32_16x16x32_bf16(a[m], b[n], acc3[m][n], 0, 0, 0);
      }
      #pragma unroll
      for (int n = 0; n < 2; ++n) {
        int col = hf * 128 + wave * 32 + n * 16 + ln;
        float b3v = b3[k * LATENT + col];
        #pragma unroll
        for (int m = 0; m < 4; ++m)
          #pragma unroll
          for (int r = 0; r < 4; ++r)
            accO[m][hf * 2 + n][r] += pv[m][r] * (acc3[m][n][r] + b3v);
      }
      if (hf == 0) {
        __syncthreads();
        #pragma unroll
        for (int i = 0; i < 8; ++i) {
          int rbase = (wave * 8 + i) * 4;
          int row = rbase + rloc;
          int src = pos ^ (row & 15);
          async16(w3k + (size_t)(128 + row) * HID + src * 8, &sm.Wbuf[rbase * HID]);
        }
        __syncthreads();
      }
    }
    __syncthreads();   // protect H1s/H2s/Wbuf before next expert
  }

  #pragma unroll
  for (int m = 0; m < 4; ++m)
    #pragma unroll
    for (int j = 0; j < 4; ++j) {
      int col = (j >> 1) * 128 + wave * 32 + (j & 1) * 16 + ln;
      #pragma unroll
      for (int r = 0; r < 4; ++r)
        out[(size_t)(row0 + m * 16 + q * 4 + r) * LATENT + col] = accO[m][j][r];
    }
}

extern "C" void kernel_launch(void* const* d_in, const int* in_sizes, int n_in,
                              void* d_out, int out_size, void* d_ws, size_t ws_size,
                              hipStream_t stream) {
  const float* cond  = (const float*)d_in[0];
  const float* u     = (const float*)d_in[1];
  const float* tau   = (const float*)d_in[2];
  const float* p_hat = (const float*)d_in[3];
  const float* W1    = (const float*)d_in[4];
  const float* b1    = (const float*)d_in[5];
  const float* W2    = (const float*)d_in[6];
  const float* b2    = (const float*)d_in[7];
  const float* W3    = (const float*)d_in[8];
  const float* b3    = (const float*)d_in[9];
  float* out = (float*)d_out;

  const size_t N1 = (size_t)KEXP * HID * EINP;    // 1,376,256
  const size_t N2 = (size_t)KEXP * HID * HID;     //   131,072
  const size_t N3 = (size_t)KEXP * LATENT * HID;  //   262,144
  const size_t NH = (size_t)32768 * NTOT;         // 33,554,432 (H1)
  if (ws_size < (N1 + N2 + N3 + NH) * sizeof(u16)) return;  // ~70.6 MB scratch

  u16* W1t = (u16*)d_ws;
  u16* W2t = W1t + N1;
  u16* W3t = W2t + N2;
  u16* H1  = W3t + N3;

  conv_w<<<W1_TILES + W2_TILES + W3_TILES, 256, 0, stream>>>(W1, W2, W3, W1t, W2t, W3t);
  h1_gemm<<<256 * 8, 256, 0, stream>>>(cond, u, tau, W1t, b1, H1);
  moe_tail<<<32768 / BM, 256, 0, stream>>>(H1, p_hat, W2t, b2, W3t, b3, out);
}

// Round 3
// 510.229 us; speedup vs baseline: 1.4426x; 1.1224x over previous
//
#include <hip/hip_runtime.h>
#include <stdint.h>

typedef unsigned short u16;
typedef __attribute__((ext_vector_type(8))) short short8;   // 8 x bf16 MFMA operand
typedef __attribute__((ext_vector_type(4))) float f32x4;    // MFMA accumulator
typedef __attribute__((ext_vector_type(4))) uint32_t u32x4;

#define KEXP   8
#define LATENT 256
#define CONDD  1024
#define HID    128
#define EIN    1281
#define EINP   1344   // 21*64, zero padded
#define NCH    21
#define NTOT   1024   // KEXP*HID

__device__ __forceinline__ u16 f2bf(float x) {              // RNE fp32->bf16
  uint32_t v = __float_as_uint(x);
  v += 0x7fffu + ((v >> 16) & 1u);
  return (u16)(v >> 16);
}

__device__ __forceinline__ void async16(const void* g, void* l) {
  __builtin_amdgcn_global_load_lds(
      (const __attribute__((address_space(1))) void*)g,
      (__attribute__((address_space(3))) void*)l, 16, 0, 0);
}

__device__ __forceinline__ float silu(float x) { return x / (1.f + __expf(-x)); }

// ---------------------------------------------------------------------------
// conv_w: coalesced 32x32 LDS-tiled transpose -> bf16.
// W1t[k][h][d]      (d padded to 1344)   from W1[k][d][h]
// W2t[k][g][h]                           from W2[k][h][g]
// W3t2[l][k*128+g]  (dense 256 x 1024)   from W3[k][g][l]
// ---------------------------------------------------------------------------
#define W1_TILES (KEXP * 42 * 4)    // 1344
#define W2_TILES (KEXP * 4 * 4)     // 128
#define W3_TILES (KEXP * 4 * 8)     // 256

__global__ void conv_w(const float* __restrict__ W1, const float* __restrict__ W2,
                       const float* __restrict__ W3,
                       u16* __restrict__ W1t, u16* __restrict__ W2t, u16* __restrict__ W3t2) {
  __shared__ float t[32][33];
  const int bid = blockIdx.x;
  const int tx = threadIdx.x & 31, ty = threadIdx.x >> 5;   // 32 x 8
  if (bid < W1_TILES) {
    int k = bid / 168, r = bid % 168;
    int d0 = (r / 4) * 32, h0 = (r % 4) * 32;
    const float* src = W1 + (size_t)k * EIN * HID;
    #pragma unroll
    for (int s = 0; s < 4; ++s) {
      int d = d0 + ty + s * 8;
      t[ty + s * 8][tx] = (d < EIN) ? src[(size_t)d * HID + h0 + tx] : 0.f;
    }
    __syncthreads();
    u16* dst = W1t + (size_t)k * HID * EINP;
    #pragma unroll
    for (int s = 0; s < 4; ++s)
      dst[(size_t)(h0 + ty + s * 8) * EINP + d0 + tx] = f2bf(t[tx][ty + s * 8]);
  } else if (bid < W1_TILES + W2_TILES) {
    int j = bid - W1_TILES;
    int k = j / 16, r = j % 16;
    int d0 = (r / 4) * 32, h0 = (r % 4) * 32;
    const float* src = W2 + (size_t)k * HID * HID;
    #pragma unroll
    for (int s = 0; s < 4; ++s)
      t[ty + s * 8][tx] = src[(size_t)(d0 + ty + s * 8) * HID + h0 + tx];
    __syncthreads();
    u16* dst = W2t + (size_t)k * HID * HID;
    #pragma unroll
    for (int s = 0; s < 4; ++s)
      dst[(size_t)(h0 + ty + s * 8) * HID + d0 + tx] = f2bf(t[tx][ty + s * 8]);
  } else {
    int j = bid - W1_TILES - W2_TILES;
    int k = j / 32, r = j % 32;
    int d0 = (r / 8) * 32, h0 = (r % 8) * 32;   // d=g (128), h=l (256)
    const float* src = W3 + (size_t)k * HID * LATENT;
    #pragma unroll
    for (int s = 0; s < 4; ++s)
      t[ty + s * 8][tx] = src[(size_t)(d0 + ty + s * 8) * LATENT + h0 + tx];
    __syncthreads();
    #pragma unroll
    for (int s = 0; s < 4; ++s)
      W3t2[(size_t)(h0 + ty + s * 8) * NTOT + k * HID + d0 + tx] = f2bf(t[tx][ty + s * 8]);
  }
}

// ---------------------------------------------------------------------------
// Kernel A: H[b][k*128+h] = silu(X @ W1t + b1), bf16. M=32768 N=1024 K=1344.
// 128x128 tile, BK=64, 32 KB LDS (two-pass epilogue) -> 4-5 blocks/CU.
// bid swizzle: the 8 expert-siblings of an m-tile are == mod 8 -> same XCD.
// ---------------------------------------------------------------------------
__global__ __launch_bounds__(256, 4)
void h1_gemm(const float* __restrict__ cond, const float* __restrict__ uu,
             const float* __restrict__ tau, const u16* __restrict__ W1t,
             const float* __restrict__ b1, u16* __restrict__ H1) {
  __shared__ union {
    struct { u16 As[128 * 64]; u16 Bs[128 * 64]; } s;   // 32 KB staging
    u16 Cs[128 * 72];                                   // 18 KB epilogue half
  } sm;

  const int tid  = threadIdx.x;
  const int wave = tid >> 6;
  const int lane = tid & 63;
  const int q    = lane >> 4;
  const int ln   = lane & 15;
  const int wm   = wave >> 1, wn = wave & 1;
  const int bid  = blockIdx.x;
  const int mt   = ((bid >> 6) << 3) | (bid & 7);   // 0..255, same-XCD siblings
  const int e    = (bid >> 3) & 7;                  // expert
  const int m0   = mt * 128, n0 = e * 128;
  const u16* w1k = W1t + (size_t)e * HID * EINP;

  const f32x4 fz = {0.f, 0.f, 0.f, 0.f};
  f32x4 acc[4][4];
  #pragma unroll
  for (int m = 0; m < 4; ++m)
    #pragma unroll
    for (int n = 0; n < 4; ++n) acc[m][n] = fz;

  #pragma unroll 1
  for (int ic = 0; ic < NCH; ++ic) {
    const int d0 = ic * 64;
    // ---- stage A (X fp32 -> bf16): 128 rows x 64 cols, 8-group XOR swizzle ----
    #pragma unroll
    for (int i = 0; i < 4; ++i) {
      int lin  = tid + i * 256;        // 0..1023
      int row  = lin >> 3;
      int gsw  = lin & 7;
      int gsrc = gsw ^ (row & 7);
      int gr   = m0 + row;
      float f0, f1, f2, f3, f4, f5, f6, f7;
      if (d0 < 256) {
        const float4* p = (const float4*)(uu + (size_t)gr * LATENT + d0 + gsrc * 8);
        float4 A = p[0], Bv = p[1];
        f0 = A.x; f1 = A.y; f2 = A.z; f3 = A.w; f4 = Bv.x; f5 = Bv.y; f6 = Bv.z; f7 = Bv.w;
      } else if (d0 < 1280) {
        const float4* p = (const float4*)(cond + (size_t)gr * CONDD + (d0 - 256) + gsrc * 8);
        float4 A = p[0], Bv = p[1];
        f0 = A.x; f1 = A.y; f2 = A.z; f3 = A.w; f4 = Bv.x; f5 = Bv.y; f6 = Bv.z; f7 = Bv.w;
      } else {
        float tv = tau[gr];
        f0 = (gsrc == 0) ? tv : 0.f;
        f1 = f2 = f3 = f4 = f5 = f6 = f7 = 0.f;
      }
      u32x4 pk;
      pk[0] = (uint32_t)f2bf(f0) | ((uint32_t)f2bf(f1) << 16);
      pk[1] = (uint32_t)f2bf(f2) | ((uint32_t)f2bf(f3) << 16);
      pk[2] = (uint32_t)f2bf(f4) | ((uint32_t)f2bf(f5) << 16);
      pk[3] = (uint32_t)f2bf(f6) | ((uint32_t)f2bf(f7) << 16);
      *(u32x4*)(&sm.s.As[row * 64 + gsw * 8]) = pk;
    }
    // ---- stage B (W1t) via async16, 8-group swizzle ----
    {
      int rloc = lane >> 3;
      int gsw  = lane & 7;
      int gsrc = gsw ^ rloc;           // row&7 == rloc
      #pragma unroll
      for (int i = 0; i < 4; ++i) {
        int rbase = (wave * 4 + i) * 8;
        async16(w1k + (size_t)(rbase + rloc) * EINP + d0 + gsrc * 8,
                &sm.s.Bs[rbase * 64]);
      }
    }
    __syncthreads();
    #pragma unroll
    for (int ks = 0; ks < 2; ++ks) {
      short8 a[4], b[4];
      #pragma unroll
      for (int m = 0; m < 4; ++m) {
        int r = wm * 64 + m * 16 + ln;
        int g = (ks * 4 + q) ^ (r & 7);
        a[m] = *(const short8*)(&sm.s.As[r * 64 + g * 8]);
      }
      #pragma unroll
      for (int n = 0; n < 4; ++n) {
        int c = wn * 64 + n * 16 + ln;
        int g = (ks * 4 + q) ^ (c & 7);
        b[n] = *(const short8*)(&sm.s.Bs[c * 64 + g * 8]);
      }
      #pragma unroll
      for (int m = 0; m < 4; ++m)
        #pragma unroll
        for (int n = 0; n < 4; ++n)
          acc[m][n] = __builtin_amdgcn_mfma_f32_16x16x32_bf16(a[m], b[n], acc[m][n], 0, 0, 0);
    }
    __syncthreads();
  }

  // ---- epilogue: silu+bias -> bf16, two 64-col passes through 18 KB Cs ----
  #pragma unroll 1
  for (int hf = 0; hf < 2; ++hf) {
    if (wn == hf) {
      #pragma unroll
      for (int n = 0; n < 4; ++n) {
        int cl = n * 16 + ln;          // local col in half
        float bv = b1[n0 + hf * 64 + cl];
        #pragma unroll
        for (int m = 0; m < 4; ++m)
          #pragma unroll
          for (int r = 0; r < 4; ++r)
            sm.Cs[(wm * 64 + m * 16 + q * 4 + r) * 72 + cl] = f2bf(silu(acc[m][n][r] + bv));
      }
    }
    __syncthreads();
    #pragma unroll
    for (int i = 0; i < 4; ++i) {
      int lin = tid + i * 256;         // 0..1023 = 128 rows x 8 groups
      int row = lin >> 3;
      int grp = lin & 7;
      *(u32x4*)(H1 + (size_t)(m0 + row) * NTOT + n0 + hf * 64 + grp * 8) =
          *(const u32x4*)(&sm.Cs[row * 72 + grp * 8]);
    }
    __syncthreads();
  }
}

// ---------------------------------------------------------------------------
// Kernel B: in-place gate fold. H[:, e*128:] <- p[:,e] * silu(H @ W2t[e] + b2).
// 128x128 tile, K=128 (2 BK-chunks), ~33 KB LDS -> 4 blocks/CU.
// ---------------------------------------------------------------------------
__global__ __launch_bounds__(256, 4)
void h2_gemm(u16* __restrict__ H, const float* __restrict__ p_hat,
             const u16* __restrict__ W2t, const float* __restrict__ b2) {
  __shared__ struct {
    union { struct { u16 As[128 * 64]; u16 Bs[128 * 64]; } s; u16 Cs[128 * 72]; } u;
    float Ps[128];
  } sm;

  const int tid  = threadIdx.x;
  const int wave = tid >> 6;
  const int lane = tid & 63;
  const int q    = lane >> 4;
  const int ln   = lane & 15;
  const int wm   = wave >> 1, wn = wave & 1;
  const int mt   = blockIdx.x >> 3;
  const int e    = blockIdx.x & 7;
  const int row0 = mt * 128;

  if (tid < 128) sm.Ps[tid] = p_hat[(size_t)(row0 + tid) * KEXP + e];

  const u16* w2k = W2t + (size_t)e * HID * HID;
  u16* hb = H + (size_t)row0 * NTOT + e * HID;

  const f32x4 fz = {0.f, 0.f, 0.f, 0.f};
  f32x4 acc[4][4];
  #pragma unroll
  for (int m = 0; m < 4; ++m)
    #pragma unroll
    for (int n = 0; n < 4; ++n) acc[m][n] = fz;

  const int rloc = lane >> 3;
  const int gsw  = lane & 7;
  const int gsrc = gsw ^ rloc;

  #pragma unroll 1
  for (int kc = 0; kc < 2; ++kc) {
    #pragma unroll
    for (int i = 0; i < 4; ++i) {
      int rbase = (wave * 4 + i) * 8;
      async16(hb + (size_t)(rbase + rloc) * NTOT + kc * 64 + gsrc * 8,
              &sm.u.s.As[rbase * 64]);
      async16(w2k + (size_t)(rbase + rloc) * HID + kc * 64 + gsrc * 8,
              &sm.u.s.Bs[rbase * 64]);
    }
    __syncthreads();
    #pragma unroll
    for (int ks = 0; ks < 2; ++ks) {
      short8 a[4], b[4];
      #pragma unroll
      for (int m = 0; m < 4; ++m) {
        int r = wm * 64 + m * 16 + ln;
        int g = (ks * 4 + q) ^ (r & 7);
        a[m] = *(const short8*)(&sm.u.s.As[r * 64 + g * 8]);
      }
      #pragma unroll
      for (int n = 0; n < 4; ++n) {
        int c = wn * 64 + n * 16 + ln;
        int g = (ks * 4 + q) ^ (c & 7);
        b[n] = *(const short8*)(&sm.u.s.Bs[c * 64 + g * 8]);
      }
      #pragma unroll
      for (int m = 0; m < 4; ++m)
        #pragma unroll
        for (int n = 0; n < 4; ++n)
          acc[m][n] = __builtin_amdgcn_mfma_f32_16x16x32_bf16(a[m], b[n], acc[m][n], 0, 0, 0);
    }
    __syncthreads();
  }

  // ---- epilogue: p * silu(acc + b2) -> bf16, in-place, two passes ----
  #pragma unroll 1
  for (int hf = 0; hf < 2; ++hf) {
    if (wn == hf) {
      #pragma unroll
      for (int n = 0; n < 4; ++n) {
        int cl = n * 16 + ln;
        float bv = b2[e * HID + hf * 64 + cl];
        #pragma unroll
        for (int m = 0; m < 4; ++m)
          #pragma unroll
          for (int r = 0; r < 4; ++r) {
            int row = wm * 64 + m * 16 + q * 4 + r;
            sm.u.Cs[row * 72 + cl] = f2bf(sm.Ps[row] * silu(acc[m][n][r] + bv));
          }
      }
    }
    __syncthreads();
    #pragma unroll
    for (int i = 0; i < 4; ++i) {
      int lin = tid + i * 256;
      int row = lin >> 3;
      int grp = lin & 7;
      *(u32x4*)(hb + (size_t)row * NTOT + hf * 64 + grp * 8) =
          *(const u32x4*)(&sm.u.Cs[row * 72 + grp * 8]);
    }
    __syncthreads();
  }
}

// ---------------------------------------------------------------------------
// Kernel C: out = Hg @ W3t2^T + (p @ b3). M=32768 N=256 K=1024.
// 64x128 tiles -> 1024 blocks, 30 KB LDS -> 4-5 blocks/CU.
// bid swizzle: the 2 n-siblings of an m-tile land on the same XCD.
// ---------------------------------------------------------------------------
__global__ __launch_bounds__(256, 4)
void out_gemm(const u16* __restrict__ H, const float* __restrict__ p_hat,
              const u16* __restrict__ W3t2, const float* __restrict__ b3,
              float* __restrict__ out) {
  __shared__ struct {
    u16 As[64 * 64];      // 8 KB
    u16 Bs[128 * 64];     // 16 KB
    float Ps[64 * 8];     // 2 KB
    float B3s[128 * 8];   // 4 KB
  } sm;

  const int tid  = threadIdx.x;
  const int wave = tid >> 6;
  const int lane = tid & 63;
  const int q    = lane >> 4;
  const int ln   = lane & 15;
  const int bid  = blockIdx.x;
  const int mt   = ((bid >> 4) << 3) | (bid & 7);   // 0..511
  const int bn   = (bid >> 3) & 1;
  const int m0   = mt * 64, n0 = bn * 128;

  // stage p rows (64 x 8) and b3 columns (128 x 8, transposed)
  if (tid < 128) {
    int row = tid >> 1, h = tid & 1;
    *(float4*)(&sm.Ps[row * 8 + h * 4]) = *(const float4*)(p_hat + (size_t)(m0 + row) * KEXP + h * 4);
  }
  #pragma unroll
  for (int i = 0; i < 4; ++i) {
    int k = i * 2 + (tid >> 7);
    int c = tid & 127;
    sm.B3s[c * 8 + k] = b3[k * LATENT + n0 + c];
  }

  const f32x4 fz = {0.f, 0.f, 0.f, 0.f};
  f32x4 acc[4][2];
  #pragma unroll
  for (int m = 0; m < 4; ++m) { acc[m][0] = fz; acc[m][1] = fz; }

  const int rloc = lane >> 3;
  const int gsw  = lane & 7;
  const int gsrc = gsw ^ rloc;

  #pragma unroll 1
  for (int kc = 0; kc < 16; ++kc) {
    #pragma unroll
    for (int i = 0; i < 2; ++i) {
      int rbase = (wave * 2 + i) * 8;
      async16(H + (size_t)(m0 + rbase + rloc) * NTOT + kc * 64 + gsrc * 8,
              &sm.As[rbase * 64]);
    }
    #pragma unroll
    for (int i = 0; i < 4; ++i) {
      int rbase = (wave * 4 + i) * 8;
      async16(W3t2 + (size_t)(n0 + rbase + rloc) * NTOT + kc * 64 + gsrc * 8,
              &sm.Bs[rbase * 64]);
    }
    __syncthreads();
    #pragma unroll
    for (int ks = 0; ks < 2; ++ks) {
      short8 a[4], b[2];
      #pragma unroll
      for (int m = 0; m < 4; ++m) {
        int r = m * 16 + ln;
        int g = (ks * 4 + q) ^ (r & 7);
        a[m] = *(const short8*)(&sm.As[r * 64 + g * 8]);
      }
      #pragma unroll
      for (int n = 0; n < 2; ++n) {
        int c = wave * 32 + n * 16 + ln;
        int g = (ks * 4 + q) ^ (c & 7);
        b[n] = *(const short8*)(&sm.Bs[c * 64 + g * 8]);
      }
      #pragma unroll
      for (int m = 0; m < 4; ++m)
        #pragma unroll
        for (int n = 0; n < 2; ++n)
          acc[m][n] = __builtin_amdgcn_mfma_f32_16x16x32_bf16(a[m], b[n], acc[m][n], 0, 0, 0);
    }
    __syncthreads();
  }

  // ---- epilogue: + sum_k p[row][k]*b3[k][col], fp32 store ----
  #pragma unroll
  for (int n = 0; n < 2; ++n) {
    int col = wave * 32 + n * 16 + ln;
    float4 c0 = *(const float4*)(&sm.B3s[col * 8]);
    float4 c1 = *(const float4*)(&sm.B3s[col * 8 + 4]);
    #pragma unroll
    for (int m = 0; m < 4; ++m)
      #pragma unroll
      for (int r = 0; r < 4; ++r) {
        int row = m * 16 + q * 4 + r;
        float4 p0 = *(const float4*)(&sm.Ps[row * 8]);
        float4 p1 = *(const float4*)(&sm.Ps[row * 8 + 4]);
        float v = acc[m][n][r]
                + p0.x * c0.x + p0.y * c0.y + p0.z * c0.z + p0.w * c0.w
                + p1.x * c1.x + p1.y * c1.y + p1.z * c1.z + p1.w * c1.w;
        out[(size_t)(m0 + row) * LATENT + n0 + col] = v;
      }
  }
}

extern "C" void kernel_launch(void* const* d_in, const int* in_sizes, int n_in,
                              void* d_out, int out_size, void* d_ws, size_t ws_size,
                              hipStream_t stream) {
  const float* cond  = (const float*)d_in[0];
  const float* u     = (const float*)d_in[1];
  const float* tau   = (const float*)d_in[2];
  const float* p_hat = (const float*)d_in[3];
  const float* W1    = (const float*)d_in[4];
  const float* b1    = (const float*)d_in[5];
  const float* W2    = (const float*)d_in[6];
  const float* b2    = (const float*)d_in[7];
  const float* W3    = (const float*)d_in[8];
  const float* b3    = (const float*)d_in[9];
  float* out = (float*)d_out;

  const size_t N1 = (size_t)KEXP * HID * EINP;    // 1,376,256
  const size_t N2 = (size_t)KEXP * HID * HID;     //   131,072
  const size_t N3 = (size_t)LATENT * NTOT;        //   262,144
  const size_t NH = (size_t)32768 * NTOT;         // 33,554,432
  if (ws_size < (N1 + N2 + N3 + NH) * sizeof(u16)) return;  // 70.6 MB (same as R2)

  u16* W1t  = (u16*)d_ws;
  u16* W2t  = W1t + N1;
  u16* W3t2 = W2t + N2;
  u16* H    = W3t2 + N3;

  conv_w<<<W1_TILES + W2_TILES + W3_TILES, 256, 0, stream>>>(W1, W2, W3, W1t, W2t, W3t2);
  h1_gemm<<<2048, 256, 0, stream>>>(cond, u, tau, W1t, b1, H);
  h2_gemm<<<2048, 256, 0, stream>>>(H, p_hat, W2t, b2);
  out_gemm<<<1024, 256, 0, stream>>>(H, p_hat, W3t2, b3, out);
}